// Round 13
// baseline (135.296 us; speedup 1.0000x reference)
//
#include <hip/hip_runtime.h>

#define N_NODES 100000
#define N_EDGES 1600000
#define IN_F 256
#define OUT_F 128

// two-level counting sort params
#define NBUCK 391            // ceil(N_NODES / 256): coarse bucket = dst >> 8
#define NCHUNK 256           // edge chunks
#define CHUNK_E (N_EDGES / NCHUNK)  // 6250
#define NSCAN (NBUCK * NCHUNK)      // 100096 count-matrix entries (mult of 16)
#define SCAN_BLK 4096        // elems per scan1 block
#define NSCAN_BLOCKS ((NSCAN + SCAN_BLK - 1) / SCAN_BLK)  // 25

#define GEMM_BM 128
#define GEMM_BLOCKS ((N_NODES + GEMM_BM - 1) / GEMM_BM)   // 782

typedef __attribute__((ext_vector_type(8))) short bf16x8;
typedef __attribute__((ext_vector_type(4))) float f32x4;

__device__ __forceinline__ unsigned short f2bf(float f) {
    unsigned u = __float_as_uint(f);
    unsigned r = u + 0x7fffu + ((u >> 16) & 1u);  // RNE
    return (unsigned short)(r >> 16);
}

// ---------------------------------------------------------------------------
// K1: count (blocks 0..255)  ∥  wtrans (blocks 256..383)
// ---------------------------------------------------------------------------
__global__ __launch_bounds__(256) void count_wtrans_kernel(const int* __restrict__ rowi,
                                                           int* __restrict__ counts,
                                                           const float* __restrict__ w,
                                                           unsigned short* __restrict__ wt) {
    const int tid = threadIdx.x;
    if (blockIdx.x >= NCHUNK) {
        int c = blockIdx.x - NCHUNK;  // 0..127
        wt[c * IN_F + tid] = f2bf(w[tid * OUT_F + c]);
        return;
    }
    __shared__ int hist[NBUCK];
    const int c = blockIdx.x;
    for (int i = tid; i < NBUCK; i += 256) hist[i] = 0;
    __syncthreads();
    const int e0 = c * CHUNK_E;
    for (int i = tid; i < CHUNK_E; i += 256)
        atomicAdd(&hist[rowi[e0 + i] >> 8], 1);
    __syncthreads();
    for (int i = tid; i < NBUCK; i += 256) counts[i * NCHUNK + c] = hist[i];
}

// ---------------------------------------------------------------------------
// K2: scan1 — per-block (4096 elems) exclusive scan in place + block sums.
// ---------------------------------------------------------------------------
__global__ __launch_bounds__(256) void scan1_kernel(int* __restrict__ data,
                                                    int* __restrict__ blocksums,
                                                    int n) {
    __shared__ int sdata[256];
    const int tid = threadIdx.x;
    const int base = blockIdx.x * SCAN_BLK + tid * 16;
    int v[16];
    if (base < n) {
#pragma unroll
        for (int q = 0; q < 4; ++q) {
            int4 t = *reinterpret_cast<const int4*>(&data[base + q * 4]);
            v[q * 4 + 0] = t.x; v[q * 4 + 1] = t.y; v[q * 4 + 2] = t.z; v[q * 4 + 3] = t.w;
        }
    } else {
#pragma unroll
        for (int i = 0; i < 16; ++i) v[i] = 0;
    }
    int pre[16], run = 0;
#pragma unroll
    for (int i = 0; i < 16; ++i) { pre[i] = run; run += v[i]; }
    sdata[tid] = run;
    __syncthreads();
#pragma unroll
    for (int off = 1; off < 256; off <<= 1) {
        int t = (tid >= off) ? sdata[tid - off] : 0;
        __syncthreads();
        sdata[tid] += t;
        __syncthreads();
    }
    int excl = (tid == 0) ? 0 : sdata[tid - 1];
    if (base < n) {
#pragma unroll
        for (int q = 0; q < 4; ++q) {
            int4 t = {excl + pre[q * 4 + 0], excl + pre[q * 4 + 1],
                      excl + pre[q * 4 + 2], excl + pre[q * 4 + 3]};
            *reinterpret_cast<int4*>(&data[base + q * 4]) = t;
        }
    }
    if (tid == 255) blocksums[blockIdx.x] = sdata[255];
}

// ---------------------------------------------------------------------------
// K3: scan2 — single block exclusive scan of nblk (<=256) block sums.
// ---------------------------------------------------------------------------
__global__ __launch_bounds__(256) void scan2_kernel(int* __restrict__ blocksums, int nblk) {
    __shared__ int sdata[256];
    const int tid = threadIdx.x;
    sdata[tid] = (tid < nblk) ? blocksums[tid] : 0;
    __syncthreads();
#pragma unroll
    for (int off = 1; off < 256; off <<= 1) {
        int t = (tid >= off) ? sdata[tid - off] : 0;
        __syncthreads();
        sdata[tid] += t;
        __syncthreads();
    }
    if (tid < nblk) blocksums[tid] = (tid == 0) ? 0 : sdata[tid - 1];
}

// ---------------------------------------------------------------------------
// K4: scatter1 (blocks 0..255)  ∥  gemm (blocks 256..1037), 512 threads.
// gemm: BM=128, 8 waves, each wave owns 16 rows x all 128 cols.
// - wt (64 KB bf16, entire K=256) staged in LDS ONCE, XOR-swizzled
//   (slot = chunk ^ (col&7)) to spread the 512B col-stride across banks.
// - ONE barrier total; the k-loop is barrier-free: A-fragments are read
//   per-wave straight from global x into registers (rows are wave-exclusive,
//   read exactly once), converted f32->bf16 in VALU.
// ---------------------------------------------------------------------------
__global__ __launch_bounds__(512, 4) void gemm_scatter_kernel(const float* __restrict__ x,
                                                              const unsigned short* __restrict__ wt,
                                                              unsigned short* __restrict__ support,
                                                              const int* __restrict__ rowi,
                                                              const int* __restrict__ coli,
                                                              const float* __restrict__ val,
                                                              const int* __restrict__ counts,
                                                              const int* __restrict__ blocksums,
                                                              uint2* __restrict__ tmp) {
    __shared__ unsigned short ws[128 * 256];  // 64 KB: [col][swizzled 16B chunk]
    __shared__ int cur[NBUCK];                // scatter path only

    const int tid = threadIdx.x;

    if (blockIdx.x < NCHUNK) {
        // ----- scatter1 (512 threads) -----
        const int c = blockIdx.x;
        for (int i = tid; i < NBUCK; i += 512) {
            int j = i * NCHUNK + c;
            cur[i] = counts[j] + blocksums[j >> 12];
        }
        __syncthreads();
        const int e0 = c * CHUNK_E;
        for (int i = tid; i < CHUNK_E; i += 512) {
            int e = e0 + i;
            int dst = rowi[e];
            int b = dst >> 8;
            int pos = atomicAdd(&cur[b], 1);
            tmp[pos] = make_uint2(((unsigned)(dst & 255) << 17) | (unsigned)coli[e],
                                  __float_as_uint(val[e]));
        }
        return;
    }

    // ----- gemm -----
    const int lane = tid & 63;
    const int wv = tid >> 6;        // wave 0..7 -> rows wv*16..+15
    const int row0 = (blockIdx.x - NCHUNK) * GEMM_BM;
    const int l15 = lane & 15;
    const int kq = lane >> 4;       // k-quarter (frag loads) / row-quad (epilogue)

    // stage全 wt into LDS, swizzled: chunk c of col stored at slot c^(col&7)
#pragma unroll
    for (int it = 0; it < 8; ++it) {
        int ci = it * 512 + tid;          // 16B-chunk index 0..4095
        int col = ci >> 5, ch = ci & 31;  // col 0..127, chunk 0..31
        uint4 v = *reinterpret_cast<const uint4*>(&wt[col * IN_F + ch * 8]);
        int slot = ch ^ (col & 7);
        *reinterpret_cast<uint4*>(&ws[col * 256 + slot * 8]) = v;
    }
    __syncthreads();  // the ONLY barrier

    int arow = row0 + wv * 16 + l15;
    if (arow > N_NODES - 1) arow = N_NODES - 1;
    const float* xrow = &x[(size_t)arow * IN_F + kq * 8];

    f32x4 acc[8];
#pragma unroll
    for (int n = 0; n < 8; ++n) acc[n] = (f32x4){0.f, 0.f, 0.f, 0.f};

#pragma unroll
    for (int kt = 0; kt < 8; ++kt) {
        f32x4 a0 = *reinterpret_cast<const f32x4*>(xrow + kt * 32);
        f32x4 a1 = *reinterpret_cast<const f32x4*>(xrow + kt * 32 + 4);
        bf16x8 af;
        af[0] = (short)f2bf(a0[0]); af[1] = (short)f2bf(a0[1]);
        af[2] = (short)f2bf(a0[2]); af[3] = (short)f2bf(a0[3]);
        af[4] = (short)f2bf(a1[0]); af[5] = (short)f2bf(a1[1]);
        af[6] = (short)f2bf(a1[2]); af[7] = (short)f2bf(a1[3]);
#pragma unroll
        for (int n = 0; n < 8; ++n) {
            int col = n * 16 + l15;
            int slot = (kt * 4 + kq) ^ (col & 7);
            bf16x8 bfv = *reinterpret_cast<const bf16x8*>(&ws[col * 256 + slot * 8]);
            acc[n] = __builtin_amdgcn_mfma_f32_16x16x32_bf16(af, bfv, acc[n], 0, 0, 0);
        }
    }

    // epilogue: C/D layout col=lane&15, row=(lane>>4)*4+r
#pragma unroll
    for (int r = 0; r < 4; ++r) {
        int row = row0 + wv * 16 + kq * 4 + r;
        if (row < N_NODES) {
#pragma unroll
            for (int n = 0; n < 8; ++n) {
                support[(size_t)row * OUT_F + n * 16 + l15] = f2bf(acc[n][r]);
            }
        }
    }
}

// ---------------------------------------------------------------------------
// K5: fine sort within one 256-node bucket; writes per-node end offsets.
// ---------------------------------------------------------------------------
__global__ __launch_bounds__(256) void fine_kernel(const uint2* __restrict__ tmp,
                                                   const int* __restrict__ counts,
                                                   const int* __restrict__ blocksums,
                                                   uint2* __restrict__ pairs,
                                                   int* __restrict__ offsets) {
    __shared__ int hist[256];
    __shared__ int scanb[256];
    __shared__ int cur[256];
    const int tid = threadIdx.x, b = blockIdx.x;
    int j0 = b * NCHUNK;
    const int start = counts[j0] + blocksums[j0 >> 12];
    int end;
    if (b == NBUCK - 1) end = N_EDGES;
    else {
        int j1 = (b + 1) * NCHUNK;
        end = counts[j1] + blocksums[j1 >> 12];
    }

    hist[tid] = 0;
    __syncthreads();
    for (int i = start + tid; i < end; i += 256)
        atomicAdd(&hist[tmp[i].x >> 17], 1);
    __syncthreads();
    int h = hist[tid];
    scanb[tid] = h;
    __syncthreads();
#pragma unroll
    for (int off = 1; off < 256; off <<= 1) {
        int t = (tid >= off) ? scanb[tid - off] : 0;
        __syncthreads();
        scanb[tid] += t;
        __syncthreads();
    }
    cur[tid] = start + scanb[tid] - h;
    int node = (b << 8) + tid;
    if (node < N_NODES) offsets[node] = start + scanb[tid];
    __syncthreads();
    for (int i = start + tid; i < end; i += 256) {
        uint2 u = tmp[i];
        int dl = u.x >> 17;
        int pos = atomicAdd(&cur[dl], 1);
        pairs[pos] = make_uint2(u.x & 0x1FFFFu, u.y);
    }
}

// ---------------------------------------------------------------------------
// K6: accumulate: one wave64 per node, 4 edge slots x 16 lanes (8 feats each),
// x2 unroll -> 8 gathers in flight per wave. (round-6 proven)
// ---------------------------------------------------------------------------
__global__ __launch_bounds__(256) void accum_kernel(const unsigned short* __restrict__ support,
                                                    const uint2* __restrict__ pairs,
                                                    const int* __restrict__ offsets,
                                                    const float* __restrict__ bias,
                                                    float* __restrict__ out) {
    const int node = blockIdx.x * 4 + (threadIdx.x >> 6);
    const int lane = threadIdx.x & 63;
    const int grp = lane >> 4;   // edge slot 0..3
    const int l16 = lane & 15;   // feats l16*8 .. l16*8+7
    if (node >= N_NODES) return;

    const int start = (node == 0) ? 0 : offsets[node - 1];
    const int end = offsets[node];

    float acc[8];
#pragma unroll
    for (int t = 0; t < 8; ++t) acc[t] = 0.f;

    int j = start + grp;
    for (; j + 4 < end; j += 8) {
        uint2 p0 = pairs[j];
        uint2 p1 = pairs[j + 4];
        uint4 s0 = *reinterpret_cast<const uint4*>(&support[(size_t)p0.x * OUT_F + l16 * 8]);
        uint4 s1 = *reinterpret_cast<const uint4*>(&support[(size_t)p1.x * OUT_F + l16 * 8]);
        float v0 = __uint_as_float(p0.y);
        float v1 = __uint_as_float(p1.y);
        unsigned u0[4] = {s0.x, s0.y, s0.z, s0.w};
        unsigned u1[4] = {s1.x, s1.y, s1.z, s1.w};
#pragma unroll
        for (int q = 0; q < 4; ++q) {
            acc[2 * q + 0] += __uint_as_float(u0[q] << 16) * v0;
            acc[2 * q + 1] += __uint_as_float(u0[q] & 0xffff0000u) * v0;
            acc[2 * q + 0] += __uint_as_float(u1[q] << 16) * v1;
            acc[2 * q + 1] += __uint_as_float(u1[q] & 0xffff0000u) * v1;
        }
    }
    for (; j < end; j += 4) {
        uint2 p0 = pairs[j];
        uint4 s0 = *reinterpret_cast<const uint4*>(&support[(size_t)p0.x * OUT_F + l16 * 8]);
        float v0 = __uint_as_float(p0.y);
        unsigned u0[4] = {s0.x, s0.y, s0.z, s0.w};
#pragma unroll
        for (int q = 0; q < 4; ++q) {
            acc[2 * q + 0] += __uint_as_float(u0[q] << 16) * v0;
            acc[2 * q + 1] += __uint_as_float(u0[q] & 0xffff0000u) * v0;
        }
    }

#pragma unroll
    for (int t = 0; t < 8; ++t) {
        acc[t] += __shfl_xor(acc[t], 16);
        acc[t] += __shfl_xor(acc[t], 32);
    }

    if (grp == 0) {
        float4 b0 = *reinterpret_cast<const float4*>(&bias[l16 * 8]);
        float4 b1 = *reinterpret_cast<const float4*>(&bias[l16 * 8 + 4]);
        f32x4 o0 = {acc[0] + b0.x, acc[1] + b0.y, acc[2] + b0.z, acc[3] + b0.w};
        f32x4 o1 = {acc[4] + b1.x, acc[5] + b1.y, acc[6] + b1.z, acc[7] + b1.w};
        f32x4* op = reinterpret_cast<f32x4*>(&out[(size_t)node * OUT_F + l16 * 8]);
        __builtin_nontemporal_store(o0, op);
        __builtin_nontemporal_store(o1, op + 1);
    }
}

extern "C" void kernel_launch(void* const* d_in, const int* in_sizes, int n_in,
                              void* d_out, int out_size, void* d_ws, size_t ws_size,
                              hipStream_t stream) {
    const float* x       = (const float*)d_in[0];
    const float* weight  = (const float*)d_in[1];
    const float* bias    = (const float*)d_in[2];
    const float* adj_val = (const float*)d_in[3];
    const int*   adj_row = (const int*)d_in[4];
    const int*   adj_col = (const int*)d_in[5];
    float* out = (float*)d_out;

    unsigned short* support = (unsigned short*)d_ws;
    unsigned short* wt = support + (size_t)N_NODES * OUT_F;
    int* counts = (int*)(wt + IN_F * OUT_F);
    int* blocksums = counts + NSCAN;
    int* offsets = blocksums + 32;
    uint2* tmp = (uint2*)(offsets + 100000);
    uint2* pairs = tmp + N_EDGES;

    // K1: count ∥ wtrans
    count_wtrans_kernel<<<NCHUNK + OUT_F, 256, 0, stream>>>(adj_row, counts, weight, wt);
    // K2/K3: scan
    scan1_kernel<<<NSCAN_BLOCKS, 256, 0, stream>>>(counts, blocksums, NSCAN);
    scan2_kernel<<<1, 256, 0, stream>>>(blocksums, NSCAN_BLOCKS);
    // K4: scatter1 ∥ gemm (barrier-free k-loop, w resident in LDS)
    gemm_scatter_kernel<<<NCHUNK + GEMM_BLOCKS, 512, 0, stream>>>(
        x, wt, support, adj_row, adj_col, adj_val, counts, blocksums, tmp);
    // K5: fine sort per bucket
    fine_kernel<<<NBUCK, 256, 0, stream>>>(tmp, counts, blocksums, pairs, offsets);
    // K6: accumulate per destination node
    accum_kernel<<<(N_NODES + 3) / 4, 256, 0, stream>>>(support, pairs, offsets, bias, out);
}